// Round 1
// 860.275 us; speedup vs baseline: 17.4274x; 17.4274x over previous
//
#include <hip/hip_runtime.h>
#include <hip/hip_bf16.h>
#include <cstdint>
#include <cstddef>

typedef __bf16 bf16_t;
typedef __bf16 bf16x8 __attribute__((ext_vector_type(8)));
typedef __bf16 bf16x4 __attribute__((ext_vector_type(4)));
typedef float  floatx4 __attribute__((ext_vector_type(4)));

#define DEV static __device__ __forceinline__

DEV float sigm(float x) { return 1.f / (1.f + __expf(-x)); }

constexpr int E_ = 80000;   // edges
constexpr int N_ = 40000;   // nodes
// H = 128, IN = 384, NODE_FDIM = 256, MAX_NB = 6

// ---------------------------------------------------------------------------
// detect: classify input float width (bf16 vs f32) and index width (i32/i64).
// flags[0]=1 -> floats are f32; flags[1]=1 -> idx are i64.  (unchanged)
// ---------------------------------------------------------------------------
__global__ void detect(const void* fmess, const void* bgraph, int* flags) {
  if (threadIdx.x == 0 && blockIdx.x == 0) {
    const uint16_t* w = (const uint16_t*)fmess;
    int good = 0;
    for (int j = 0; j < 128; ++j) {
      uint16_t x = w[j];
      int e = (x >> 7) & 0xFF;
      if (x == 0 || x == 0x8000 || (e >= 100 && e <= 140)) ++good;
    }
    flags[0] = (good < 110) ? 1 : 0;
    const uint32_t* q = (const uint32_t*)bgraph;
    int zeros = 0;
    for (int j = 0; j < 128; ++j)
      if (q[2 * j + 1] == 0u) ++zeros;
    flags[1] = (zeros >= 120) ? 1 : 0;
  }
}

DEV float rdf(const void* p, size_t i, bool f32) {
  return f32 ? ((const float*)p)[i] : (float)((const bf16_t*)p)[i];
}

// ---------------------------------------------------------------------------
// prep: dtype-aware transposed weight copies (BT[n][k] = W[k][n]) + bf16 bias
// copies.  WzT/WhT [128,512], WrT/WoT [128,384], UrT [128,128].  (unchanged)
// ---------------------------------------------------------------------------
__launch_bounds__(256)
__global__ void prep(const void* Wz, const void* Wr, const void* Ur,
                     const void* Wh, const void* Wo,
                     const void* bz, const void* bur, const void* bh,
                     const void* bo, const int* flags,
                     bf16_t* WzT, bf16_t* WhT, bf16_t* WrT, bf16_t* UrT,
                     bf16_t* WoT, bf16_t* bzB, bf16_t* burB, bf16_t* bhB,
                     bf16_t* boB) {
  const bool f32 = flags[0] != 0;
  int i = blockIdx.x * blockDim.x + threadIdx.x;   // 65536 threads
  {  // 128 x 512
    int j = i >> 9, k = i & 511;
    WzT[i] = (bf16_t)rdf(Wz, (size_t)k * 128 + j, f32);
    WhT[i] = (bf16_t)rdf(Wh, (size_t)k * 128 + j, f32);
  }
  if (i < 128 * 384) {
    int j = i / 384, k = i % 384;
    WrT[i] = (bf16_t)rdf(Wr, (size_t)k * 128 + j, f32);
    WoT[i] = (bf16_t)rdf(Wo, (size_t)k * 128 + j, f32);
  }
  if (i < 128 * 128) {
    int j = i >> 7, k = i & 127;
    UrT[i] = (bf16_t)rdf(Ur, (size_t)k * 128 + j, f32);
  }
  if (i < 128) {
    bzB[i]  = (bf16_t)rdf(bz, i, f32);
    burB[i] = (bf16_t)rdf(bur, i, f32);
    bhB[i]  = (bf16_t)rdf(bh, i, f32);
    boB[i]  = (bf16_t)rdf(bo, i, f32);
  }
}

// ---------------------------------------------------------------------------
// idx_cvt: normalize agraph/bgraph to int32 ws copies.  (unchanged)
// ---------------------------------------------------------------------------
__launch_bounds__(256)
__global__ void idx_cvt(const void* ag, const void* bg, int* aI, int* bI,
                        const int* flags) {
  const bool i64 = flags[1] != 0;
  int i = blockIdx.x * blockDim.x + threadIdx.x;   // 480000 threads
  if (i < N_ * 6)
    aI[i] = i64 ? (int)((const long long*)ag)[i] : ((const int*)ag)[i];
  if (i < E_ * 6)
    bI[i] = i64 ? (int)((const long long*)bg)[i] : ((const int*)bg)[i];
}

// ---------------------------------------------------------------------------
// MFMA GEMM.  C[M,128] built from 16x16x32 bf16 MFMA fragments.
//   A fragment: lane l -> row (l&15), k = (l>>4)*8 + j  (16B contiguous)
//   B fragment from B^T rows: lane l -> col (l&15), k = (l>>4)*8 + j
//   D fragment: lane l, reg r -> row (l>>4)*4 + r, col (l&15)   [m89-verified]
// Block: 256 thr = 4 waves, tile 64 rows x 128 cols; wave tile 32x64.
// No LDS: B is L1/L2-resident (<=128KB), A streamed (16 rows x 64B per load).
// ---------------------------------------------------------------------------
DEV floatx4 mfma16(bf16x8 a, bf16x8 b, floatx4 c) {
  return __builtin_amdgcn_mfma_f32_16x16x32_bf16(a, b, c, 0, 0, 0);
}

// One K-segment: acc0 += A@Ba[KOFF:KOFF+K]; if DUAL also acc1 += A@Bb[...].
// AF32: A elements are f32 (convert to bf16 in-register at load).
template <bool AF32, bool DUAL, int K, int KOFF>
DEV void gphase(const void* A, int lda,
                const bf16_t* Ba, const bf16_t* Bb, int ldb,
                int rowBase, int colBase, int lr, int kg,
                floatx4 (&acc0)[2][4], floatx4 (&acc1)[2][4]) {
  const bf16_t* bA[4];
  const bf16_t* bB[4];
#pragma unroll
  for (int n = 0; n < 4; ++n) {
    bA[n] = Ba + (size_t)(colBase + n * 16 + lr) * ldb + KOFF + kg * 8;
    if constexpr (DUAL)
      bB[n] = Bb + (size_t)(colBase + n * 16 + lr) * ldb + KOFF + kg * 8;
  }
#pragma unroll
  for (int k = 0; k < K; k += 32) {
    bf16x8 a[2];
#pragma unroll
    for (int m = 0; m < 2; ++m) {
      if constexpr (AF32) {
        const float* ap =
            (const float*)A + (size_t)(rowBase + m * 16 + lr) * lda + k + kg * 8;
        floatx4 x0 = *(const floatx4*)ap;
        floatx4 x1 = *(const floatx4*)(ap + 4);
#pragma unroll
        for (int j = 0; j < 4; ++j) {
          a[m][j]     = (bf16_t)x0[j];
          a[m][4 + j] = (bf16_t)x1[j];
        }
      } else {
        a[m] = *(const bf16x8*)((const bf16_t*)A +
                                (size_t)(rowBase + m * 16 + lr) * lda + k + kg * 8);
      }
    }
#pragma unroll
    for (int n = 0; n < 4; ++n) {
      bf16x8 b0 = *(const bf16x8*)(bA[n] + k);
#pragma unroll
      for (int m = 0; m < 2; ++m) acc0[m][n] = mfma16(a[m], b0, acc0[m][n]);
      if constexpr (DUAL) {
        bf16x8 b1 = *(const bf16x8*)(bB[n] + k);
#pragma unroll
        for (int m = 0; m < 2; ++m) acc1[m][n] = mfma16(a[m], b1, acc1[m][n]);
      }
    }
  }
}

// MODE 0: v = acc0 + bias0                       -> Cb (bf16)
// MODE 1: z  = sig(acc0 + bias0); ph = tanh(acc1 + bias1);
//         v  = (1-z)*S + z*ph; row0 = 0          -> Cb (+ optional Cf f32)
// MODE 2: v = relu(acc0 + bias0); row0 = 0       -> Cf (f32)
// Segment plan: phase1 = A0 (dyn dtype) over K0 vs Ba [and Bb if MODE1];
//               phase2 (K1>0) = A1a vs Ba[K0:] into acc0, A1b vs Bb[K0:] acc1.
template <int K0, int K1, int MODE>
__launch_bounds__(256, 2)
__global__ void mgemm(const void* A0, int lda0, int a0dyn,
                      const bf16_t* A1a, const bf16_t* A1b,
                      const bf16_t* Ba, const bf16_t* Bb, int ldb,
                      const int* flags,
                      const bf16_t* bias0, const bf16_t* bias1,
                      const bf16_t* Sb,
                      bf16_t* Cb, float* Cf) {
  int w = threadIdx.x >> 6, lane = threadIdx.x & 63;
  int lr = lane & 15, kg = lane >> 4;
  int rowBase = blockIdx.x * 64 + (w >> 1) * 32;
  int colBase = (w & 1) * 64;

  floatx4 acc0[2][4] = {};
  floatx4 acc1[2][4] = {};

  if (a0dyn && flags[0] != 0)
    gphase<true, MODE == 1, K0, 0>(A0, lda0, Ba, Bb, ldb, rowBase, colBase,
                                   lr, kg, acc0, acc1);
  else
    gphase<false, MODE == 1, K0, 0>(A0, lda0, Ba, Bb, ldb, rowBase, colBase,
                                    lr, kg, acc0, acc1);

  if constexpr (K1 > 0) {
    gphase<false, false, K1, K0>(A1a, K1, Ba, nullptr, ldb, rowBase, colBase,
                                 lr, kg, acc0, acc1);
    if constexpr (MODE == 1)
      gphase<false, false, K1, K0>(A1b, K1, Bb, nullptr, ldb, rowBase, colBase,
                                   lr, kg, acc1, acc0);
  }

#pragma unroll
  for (int m = 0; m < 2; ++m)
#pragma unroll
    for (int n = 0; n < 4; ++n) {
      int col = colBase + n * 16 + lr;
#pragma unroll
      for (int r = 0; r < 4; ++r) {
        int row = rowBase + m * 16 + kg * 4 + r;
        float v;
        if constexpr (MODE == 0) {
          v = acc0[m][n][r] + (bias0 ? (float)bias0[col] : 0.f);
        } else if constexpr (MODE == 1) {
          float z  = sigm(acc0[m][n][r] + (float)bias0[col]);
          float ph = tanhf(acc1[m][n][r] + (float)bias1[col]);
          float s  = Sb ? (float)Sb[(size_t)row * 128 + col] : 0.f;
          v = (1.f - z) * s + z * ph;
          if (row == 0) v = 0.f;
        } else {
          v = fmaxf(acc0[m][n][r] + (float)bias0[col], 0.f);
          if (row == 0) v = 0.f;
        }
        if (Cb) Cb[(size_t)row * 128 + col] = (bf16_t)v;
        if (Cf) Cf[(size_t)row * 128 + col] = v;
      }
    }
}

// ---------------------------------------------------------------------------
// Gather+reduce per edge: S = sum h_nei, T = sum sigmoid(Mr + G_nei) * h_nei
// (unchanged)
// ---------------------------------------------------------------------------
__launch_bounds__(256)
__global__ void depth_gather(const bf16_t* h, const bf16_t* G, const bf16_t* Mr,
                             const int* bgraph, bf16_t* S, bf16_t* T) {
  int t = threadIdx.x;
  int e = blockIdx.x * 8 + (t >> 5);
  int c4 = (t & 31) * 4;
  bf16x4 mr = *(const bf16x4*)(Mr + (size_t)e * 128 + c4);
  float mrf[4];
#pragma unroll
  for (int j = 0; j < 4; ++j) mrf[j] = (float)mr[j];
  float sa[4] = {0.f, 0.f, 0.f, 0.f}, ta[4] = {0.f, 0.f, 0.f, 0.f};
  const int* bg = bgraph + (size_t)e * 6;
#pragma unroll
  for (int n = 0; n < 6; ++n) {
    int idx = bg[n];
    bf16x4 h4 = *(const bf16x4*)(h + (size_t)idx * 128 + c4);
    bf16x4 g4 = *(const bf16x4*)(G + (size_t)idx * 128 + c4);
#pragma unroll
    for (int j = 0; j < 4; ++j) {
      float hv = (float)h4[j];
      float r = sigm(mrf[j] + (float)g4[j]);
      sa[j] += hv;
      ta[j] += r * hv;
    }
  }
  bf16x4 sv, tv;
#pragma unroll
  for (int j = 0; j < 4; ++j) { sv[j] = (bf16_t)sa[j]; tv[j] = (bf16_t)ta[j]; }
  *(bf16x4*)(S + (size_t)e * 128 + c4) = sv;
  *(bf16x4*)(T + (size_t)e * 128 + c4) = tv;
}

// ---------------------------------------------------------------------------
// Node gather: NM[v] = sum_n h[agraph[v,n]]   (unchanged)
// ---------------------------------------------------------------------------
__launch_bounds__(256)
__global__ void nm_gather(const bf16_t* h, const int* agraph, bf16_t* NM) {
  int t = threadIdx.x;
  int v = blockIdx.x * 8 + (t >> 5);
  int c4 = (t & 31) * 4;
  float sa[4] = {0.f, 0.f, 0.f, 0.f};
  const int* ag = agraph + (size_t)v * 6;
#pragma unroll
  for (int n = 0; n < 6; ++n) {
    int idx = ag[n];
    bf16x4 h4 = *(const bf16x4*)(h + (size_t)idx * 128 + c4);
#pragma unroll
    for (int j = 0; j < 4; ++j) sa[j] += (float)h4[j];
  }
  bf16x4 o;
#pragma unroll
  for (int j = 0; j < 4; ++j) o[j] = (bf16_t)sa[j];
  *(bf16x4*)(NM + (size_t)v * 128 + c4) = o;
}

// ---------------------------------------------------------------------------
extern "C" void kernel_launch(void* const* d_in, const int* in_sizes, int n_in,
                              void* d_out, int out_size, void* d_ws, size_t ws_size,
                              hipStream_t stream) {
  const void* fnode  = d_in[0];
  const void* fmess  = d_in[1];
  const void* agraph = d_in[2];
  const void* bgraph = d_in[3];
  const void* Wz  = d_in[4];
  const void* bz  = d_in[5];
  const void* Wr  = d_in[6];
  const void* Ur  = d_in[7];
  const void* bur = d_in[8];
  const void* Wh  = d_in[9];
  const void* bh  = d_in[10];
  const void* Wo  = d_in[11];
  const void* bo  = d_in[12];

  // workspace (~126 MB): 6 x [E,128] bf16 + weights + idx copies (unchanged)
  char* ws = (char*)d_ws;
  bf16_t* Mr  = (bf16_t*)ws; ws += (size_t)E_ * 128 * 2;  // fmess@Wr + bur
  bf16_t* G   = (bf16_t*)ws; ws += (size_t)E_ * 128 * 2;  // h@Ur; later NM
  bf16_t* S   = (bf16_t*)ws; ws += (size_t)E_ * 128 * 2;  // sum h_nei
  bf16_t* T   = (bf16_t*)ws; ws += (size_t)E_ * 128 * 2;  // sum r*h_nei
  bf16_t* hP0 = (bf16_t*)ws; ws += (size_t)E_ * 128 * 2;  // h ping
  bf16_t* hP1 = (bf16_t*)ws; ws += (size_t)E_ * 128 * 2;  // h pong
  bf16_t* WzT = (bf16_t*)ws; ws += 128 * 512 * 2;
  bf16_t* WhT = (bf16_t*)ws; ws += 128 * 512 * 2;
  bf16_t* WrT = (bf16_t*)ws; ws += 128 * 384 * 2;
  bf16_t* UrT = (bf16_t*)ws; ws += 128 * 128 * 2;
  bf16_t* WoT = (bf16_t*)ws; ws += 128 * 384 * 2;
  bf16_t* bzB  = (bf16_t*)ws; ws += 128 * 2;
  bf16_t* burB = (bf16_t*)ws; ws += 128 * 2;
  bf16_t* bhB  = (bf16_t*)ws; ws += 128 * 2;
  bf16_t* boB  = (bf16_t*)ws; ws += 128 * 2;
  int* aI    = (int*)ws; ws += (size_t)N_ * 6 * 4;
  int* bI    = (int*)ws; ws += (size_t)E_ * 6 * 4;
  int* flags = (int*)ws; ws += 16;

  // OUTPUT AS F32: out0 [N,128] then h [E,128]
  float* out0F = (float*)d_out;
  float* hOutF = out0F + (size_t)N_ * 128;
  bf16_t* NM   = G;   // alias: G dead before nm_gather

  detect<<<1, 64, 0, stream>>>(fmess, bgraph, flags);
  prep<<<256, 256, 0, stream>>>(Wz, Wr, Ur, Wh, Wo, bz, bur, bh, bo, flags,
                                WzT, WhT, WrT, UrT, WoT, bzB, burB, bhB, boB);
  idx_cvt<<<1875, 256, 0, stream>>>(agraph, bgraph, aI, bI, flags);

  // Mr = fmess @ Wr + bur   (loop-invariant)
  mgemm<384, 0, 0><<<E_ / 64, 256, 0, stream>>>(
      fmess, 384, 1, nullptr, nullptr, WrT, nullptr, 384, flags,
      burB, nullptr, nullptr, Mr, nullptr);

  // depth 0: h = sig(fmess@Wz1+bz) * tanh(fmess@Wh1+bh)  (sum_h = 0)
  mgemm<384, 0, 1><<<E_ / 64, 256, 0, stream>>>(
      fmess, 384, 1, nullptr, nullptr, WzT, WhT, 512, flags,
      bzB, bhB, nullptr, hP0, nullptr);

  const bf16_t* src = hP0;
  bf16_t* dst = hP1;
  for (int d = 0; d < 2; ++d) {
    // G = h @ Ur
    mgemm<128, 0, 0><<<E_ / 64, 256, 0, stream>>>(
        src, 128, 0, nullptr, nullptr, UrT, nullptr, 128, flags,
        nullptr, nullptr, nullptr, G, nullptr);

    depth_gather<<<10000, 256, 0, stream>>>(src, G, Mr, bI, S, T);

    // h' = (1-z)*S + z*tanh(fmess@Wh1 + T@Wh2 + bh),
    //  z = sig(fmess@Wz1 + S@Wz2 + bz)
    mgemm<384, 128, 1><<<E_ / 64, 256, 0, stream>>>(
        fmess, 384, 1, S, T, WzT, WhT, 512, flags,
        bzB, bhB, S, dst, (d == 1) ? hOutF : nullptr);

    src = dst;
    dst = (d == 0) ? hP0 : hP1;
  }
  const bf16_t* hFinal = hP0;   // d=1: src was hP1, dst was hP0

  nm_gather<<<5000, 256, 0, stream>>>(hFinal, aI, NM);

  // out = relu(fnode@Wo1 + NM@Wo2 + bo), row0 = 0   -> f32
  mgemm<256, 128, 2><<<N_ / 64, 256, 0, stream>>>(
      fnode, 256, 1, NM, nullptr, WoT, nullptr, 384, flags,
      boB, nullptr, nullptr, nullptr, out0F);
}

// Round 2
// 592.265 us; speedup vs baseline: 25.3136x; 1.4525x over previous
//
#include <hip/hip_runtime.h>
#include <hip/hip_bf16.h>
#include <cstdint>
#include <cstddef>

typedef __bf16 bf16_t;
typedef __bf16 bf16x8 __attribute__((ext_vector_type(8)));
typedef __bf16 bf16x4 __attribute__((ext_vector_type(4)));
typedef float  floatx4 __attribute__((ext_vector_type(4)));

#define DEV static __device__ __forceinline__

DEV float sigm(float x) { return 1.f / (1.f + __expf(-x)); }

constexpr int E_ = 80000;   // edges
constexpr int N_ = 40000;   // nodes
// H = 128, IN = 384, NODE_FDIM = 256, MAX_NB = 6

// ---------------------------------------------------------------------------
// detect: classify input float width (bf16 vs f32) and index width (i32/i64).
// flags[0]=1 -> floats are f32; flags[1]=1 -> idx are i64.  (unchanged)
// ---------------------------------------------------------------------------
__global__ void detect(const void* fmess, const void* bgraph, int* flags) {
  if (threadIdx.x == 0 && blockIdx.x == 0) {
    const uint16_t* w = (const uint16_t*)fmess;
    int good = 0;
    for (int j = 0; j < 128; ++j) {
      uint16_t x = w[j];
      int e = (x >> 7) & 0xFF;
      if (x == 0 || x == 0x8000 || (e >= 100 && e <= 140)) ++good;
    }
    flags[0] = (good < 110) ? 1 : 0;
    const uint32_t* q = (const uint32_t*)bgraph;
    int zeros = 0;
    for (int j = 0; j < 128; ++j)
      if (q[2 * j + 1] == 0u) ++zeros;
    flags[1] = (zeros >= 120) ? 1 : 0;
  }
}

DEV float rdf(const void* p, size_t i, bool f32) {
  return f32 ? ((const float*)p)[i] : (float)((const bf16_t*)p)[i];
}

// ---------------------------------------------------------------------------
// prep: dtype-aware transposed weight copies (BT[n][k] = W[k][n]) + bf16 bias
// copies.  WzT/WhT [128,512], WrT/WoT [128,384], UrT [128,128].  (unchanged)
// ---------------------------------------------------------------------------
__launch_bounds__(256)
__global__ void prep(const void* Wz, const void* Wr, const void* Ur,
                     const void* Wh, const void* Wo,
                     const void* bz, const void* bur, const void* bh,
                     const void* bo, const int* flags,
                     bf16_t* WzT, bf16_t* WhT, bf16_t* WrT, bf16_t* UrT,
                     bf16_t* WoT, bf16_t* bzB, bf16_t* burB, bf16_t* bhB,
                     bf16_t* boB) {
  const bool f32 = flags[0] != 0;
  int i = blockIdx.x * blockDim.x + threadIdx.x;   // 65536 threads
  {  // 128 x 512
    int j = i >> 9, k = i & 511;
    WzT[i] = (bf16_t)rdf(Wz, (size_t)k * 128 + j, f32);
    WhT[i] = (bf16_t)rdf(Wh, (size_t)k * 128 + j, f32);
  }
  if (i < 128 * 384) {
    int j = i / 384, k = i % 384;
    WrT[i] = (bf16_t)rdf(Wr, (size_t)k * 128 + j, f32);
    WoT[i] = (bf16_t)rdf(Wo, (size_t)k * 128 + j, f32);
  }
  if (i < 128 * 128) {
    int j = i >> 7, k = i & 127;
    UrT[i] = (bf16_t)rdf(Ur, (size_t)k * 128 + j, f32);
  }
  if (i < 128) {
    bzB[i]  = (bf16_t)rdf(bz, i, f32);
    burB[i] = (bf16_t)rdf(bur, i, f32);
    bhB[i]  = (bf16_t)rdf(bh, i, f32);
    boB[i]  = (bf16_t)rdf(bo, i, f32);
  }
}

// ---------------------------------------------------------------------------
// idx_cvt: normalize agraph/bgraph to int32 ws copies.  (unchanged)
// ---------------------------------------------------------------------------
__launch_bounds__(256)
__global__ void idx_cvt(const void* ag, const void* bg, int* aI, int* bI,
                        const int* flags) {
  const bool i64 = flags[1] != 0;
  int i = blockIdx.x * blockDim.x + threadIdx.x;   // 480000 threads
  if (i < N_ * 6)
    aI[i] = i64 ? (int)((const long long*)ag)[i] : ((const int*)ag)[i];
  if (i < E_ * 6)
    bI[i] = i64 ? (int)((const long long*)bg)[i] : ((const int*)bg)[i];
}

// ---------------------------------------------------------------------------
// cvt_bf16: f32 -> bf16 bulk convert (no-op when inputs already bf16).
// ---------------------------------------------------------------------------
__launch_bounds__(256)
__global__ void cvt_bf16(const float* src, bf16_t* dst, int n8,
                         const int* flags) {
  if (flags[0] == 0) return;
  int i = blockIdx.x * blockDim.x + threadIdx.x;
  int stride = gridDim.x * blockDim.x;
  for (; i < n8; i += stride) {
    const float* s = src + (size_t)i * 8;
    floatx4 x0 = *(const floatx4*)s;
    floatx4 x1 = *(const floatx4*)(s + 4);
    bf16x8 o;
#pragma unroll
    for (int j = 0; j < 4; ++j) { o[j] = (bf16_t)x0[j]; o[4 + j] = (bf16_t)x1[j]; }
    *(bf16x8*)(dst + (size_t)i * 8) = o;
  }
}

// ---------------------------------------------------------------------------
// MFMA GEMM, LDS double-buffered (2-phase T3-minimal structure).
//   BM=128, BN=128, BK=32.  512 thr = 8 waves as 2(m)x4(n); wave tile 64x32.
//   LDS tiles [128][32] bf16; slot-swizzle: slot s of row r holds global
//   k-quad q = s ^ ((r>>1)&3)  (2-way bank aliasing on ds_read_b128 = free).
//   Staged with global_load_lds width 16 (linear LDS dest = wave base +
//   lane*16; swizzle applied on the per-lane GLOBAL source address).
//   MFMA frag maps (verified in prior rounds): A/B lane l -> row/col l&15,
//   k=(l>>4)*8+j;  D lane l,reg r -> row (l>>4)*4+r, col l&15.
// ---------------------------------------------------------------------------
DEV void gld16(const bf16_t* g, bf16_t* l) {
  __builtin_amdgcn_global_load_lds(
      (const __attribute__((address_space(1))) void*)g,
      (__attribute__((address_space(3))) void*)l, 16, 0, 0);
}

DEV floatx4 mfma16(bf16x8 a, bf16x8 b, floatx4 c) {
  return __builtin_amdgcn_mfma_f32_16x16x32_bf16(a, b, c, 0, 0, 0);
}

// MODE 0: v = acc0 + bias0                       -> Cb (bf16)
// MODE 1: z = sig(acc0+bias0); ph = tanh(acc1+bias1);
//         v = (1-z)*S + z*ph; row0 = 0           -> Cb (+ optional Cf f32)
// MODE 2: v = relu(acc0 + bias0); row0 = 0       -> Cf (f32)
// K plan: seg1 (K0): A0 vs Ba (and Bb if MODE1, sharing A0).
//         seg2 (K1>0): A1a vs Ba[K0:] -> acc0; if MODE1: A1b vs Bb[K0:] -> acc1.
template <int K0, int K1, int MODE>
__launch_bounds__(512, 4)
__global__ void mgemm(const bf16_t* A0a, const bf16_t* A0b, int lda0,
                      const bf16_t* A1a, const bf16_t* A1b,
                      const bf16_t* Ba, const bf16_t* Bb, int ldb,
                      const int* flags,
                      const bf16_t* bias0, const bf16_t* bias1,
                      const bf16_t* Sb, bf16_t* Cb, float* Cf, int Mrows) {
  constexpr int NT0 = K0 / 32, NT1 = K1 / 32, NT = NT0 + NT1;
  constexpr int NTILES = (MODE == 1) ? (K1 > 0 ? 4 : 3) : 2;
  // tile slots: 0=A, 1=Ba, 2=Bb (MODE1), 3=A1b (MODE1 seg2)
  __shared__ bf16_t lds[2][NTILES * 128 * 32];

  const bf16_t* A0 = (flags[0] != 0) ? A0b : A0a;

  const int tid  = threadIdx.x;
  const int w    = tid >> 6, lane = tid & 63;
  const int wm   = w >> 2, wn = w & 3;          // wave tile: rows wm*64, cols wn*32
  const int lr   = lane & 15, kg = lane >> 4;
  const int rowBase = blockIdx.x * 128;

  // staging lane map: each wave stages 16 rows/cols per tile
  const int rr = lane >> 2, sq = lane & 3;
  const int r  = w * 16 + rr;                   // tile row (A) / col (B)
  const int q  = sq ^ ((r >> 1) & 3);           // global k-quad for this slot
  const int ldsOff = w * 512;                   // elems; wave-uniform base
  int gRowA = rowBase + r;
  if (gRowA > Mrows - 1) gRowA = Mrows - 1;     // MODE2 tail clamp

  floatx4 acc0[4][2] = {};
  floatx4 acc1[4][2] = {};

  auto stage = [&](int kt, int buf) {
    const bf16_t* asrc; int alda, kk;
    if (kt < NT0) { asrc = A0;  alda = lda0; kk = kt * 32; }
    else          { asrc = A1a; alda = K1;   kk = (kt - NT0) * 32; }
    gld16(asrc + (size_t)gRowA * alda + kk + q * 8, &lds[buf][0] + ldsOff);
    gld16(Ba + (size_t)r * ldb + kt * 32 + q * 8, &lds[buf][4096] + ldsOff);
    if constexpr (MODE == 1) {
      gld16(Bb + (size_t)r * ldb + kt * 32 + q * 8, &lds[buf][2 * 4096] + ldsOff);
      if constexpr (K1 > 0) {
        if (kt >= NT0)
          gld16(A1b + (size_t)gRowA * K1 + (kt - NT0) * 32 + q * 8,
                &lds[buf][3 * 4096] + ldsOff);
      }
    }
  };

  auto compute = [&](int buf, bool seg2) {
    const bf16_t* L = lds[buf];
    bf16x8 b0[2], b1[2];
#pragma unroll
    for (int ni = 0; ni < 2; ++ni) {
      int c = wn * 32 + ni * 16 + lr;
      int s = kg ^ ((c >> 1) & 3);
      b0[ni] = *(const bf16x8*)(L + 4096 + c * 32 + s * 8);
      if constexpr (MODE == 1)
        b1[ni] = *(const bf16x8*)(L + 2 * 4096 + c * 32 + s * 8);
    }
#pragma unroll
    for (int mi = 0; mi < 4; ++mi) {
      int rA = wm * 64 + mi * 16 + lr;
      int s  = kg ^ ((rA >> 1) & 3);
      bf16x8 a0 = *(const bf16x8*)(L + rA * 32 + s * 8);
#pragma unroll
      for (int ni = 0; ni < 2; ++ni)
        acc0[mi][ni] = mfma16(a0, b0[ni], acc0[mi][ni]);
      if constexpr (MODE == 1) {
        bf16x8 ah = a0;
        if (seg2) ah = *(const bf16x8*)(L + 3 * 4096 + rA * 32 + s * 8);
#pragma unroll
        for (int ni = 0; ni < 2; ++ni)
          acc1[mi][ni] = mfma16(ah, b1[ni], acc1[mi][ni]);
      }
    }
  };

  stage(0, 0);
  __syncthreads();
  int cur = 0;
  for (int kt = 0; kt < NT0; ++kt) {
    if (kt + 1 < NT) stage(kt + 1, cur ^ 1);
    compute(cur, false);
    __syncthreads();
    cur ^= 1;
  }
  if constexpr (NT1 > 0) {
    for (int kt = NT0; kt < NT; ++kt) {
      if (kt + 1 < NT) stage(kt + 1, cur ^ 1);
      compute(cur, true);
      __syncthreads();
      cur ^= 1;
    }
  }

#pragma unroll
  for (int mi = 0; mi < 4; ++mi) {
#pragma unroll
    for (int ni = 0; ni < 2; ++ni) {
      const int col = wn * 32 + ni * 16 + lr;
#pragma unroll
      for (int r4 = 0; r4 < 4; ++r4) {
        const int row = rowBase + wm * 64 + mi * 16 + kg * 4 + r4;
        if (row < Mrows) {
          float v;
          if constexpr (MODE == 0) {
            v = acc0[mi][ni][r4] + (bias0 ? (float)bias0[col] : 0.f);
          } else if constexpr (MODE == 1) {
            float z  = sigm(acc0[mi][ni][r4] + (float)bias0[col]);
            float ph = tanhf(acc1[mi][ni][r4] + (float)bias1[col]);
            float sI = Sb ? (float)Sb[(size_t)row * 128 + col] : 0.f;
            v = (1.f - z) * sI + z * ph;
            if (row == 0) v = 0.f;
          } else {
            v = fmaxf(acc0[mi][ni][r4] + (float)bias0[col], 0.f);
            if (row == 0) v = 0.f;
          }
          if (Cb) Cb[(size_t)row * 128 + col] = (bf16_t)v;
          if (Cf) Cf[(size_t)row * 128 + col] = v;
        }
      }
    }
  }
}

// ---------------------------------------------------------------------------
// Gather+reduce per edge: S = sum h_nei, T = sum sigmoid(Mr + G_nei) * h_nei
// 16 threads/edge, bf16x8 (16B) loads.
// ---------------------------------------------------------------------------
__launch_bounds__(256)
__global__ void depth_gather(const bf16_t* h, const bf16_t* G, const bf16_t* Mr,
                             const int* bgraph, bf16_t* S, bf16_t* T) {
  int t = threadIdx.x;
  int e = blockIdx.x * 16 + (t >> 4);
  int c8 = (t & 15) * 8;
  bf16x8 mr = *(const bf16x8*)(Mr + (size_t)e * 128 + c8);
  float mrf[8];
#pragma unroll
  for (int j = 0; j < 8; ++j) mrf[j] = (float)mr[j];
  float sa[8] = {}, ta[8] = {};
  const int* bg = bgraph + (size_t)e * 6;
#pragma unroll
  for (int n = 0; n < 6; ++n) {
    int idx = bg[n];
    bf16x8 h8 = *(const bf16x8*)(h + (size_t)idx * 128 + c8);
    bf16x8 g8 = *(const bf16x8*)(G + (size_t)idx * 128 + c8);
#pragma unroll
    for (int j = 0; j < 8; ++j) {
      float hv = (float)h8[j];
      float rg = sigm(mrf[j] + (float)g8[j]);
      sa[j] += hv;
      ta[j] += rg * hv;
    }
  }
  bf16x8 sv, tv;
#pragma unroll
  for (int j = 0; j < 8; ++j) { sv[j] = (bf16_t)sa[j]; tv[j] = (bf16_t)ta[j]; }
  *(bf16x8*)(S + (size_t)e * 128 + c8) = sv;
  *(bf16x8*)(T + (size_t)e * 128 + c8) = tv;
}

// ---------------------------------------------------------------------------
// Node gather: NM[v] = sum_n h[agraph[v,n]]   (16 thr/node, bf16x8 loads)
// ---------------------------------------------------------------------------
__launch_bounds__(256)
__global__ void nm_gather(const bf16_t* h, const int* agraph, bf16_t* NM) {
  int t = threadIdx.x;
  int v = blockIdx.x * 16 + (t >> 4);
  int c8 = (t & 15) * 8;
  float sa[8] = {};
  const int* ag = agraph + (size_t)v * 6;
#pragma unroll
  for (int n = 0; n < 6; ++n) {
    int idx = ag[n];
    bf16x8 h8 = *(const bf16x8*)(h + (size_t)idx * 128 + c8);
#pragma unroll
    for (int j = 0; j < 8; ++j) sa[j] += (float)h8[j];
  }
  bf16x8 o;
#pragma unroll
  for (int j = 0; j < 8; ++j) o[j] = (bf16_t)sa[j];
  *(bf16x8*)(NM + (size_t)v * 128 + c8) = o;
}

// ---------------------------------------------------------------------------
extern "C" void kernel_launch(void* const* d_in, const int* in_sizes, int n_in,
                              void* d_out, int out_size, void* d_ws, size_t ws_size,
                              hipStream_t stream) {
  const void* fnode  = d_in[0];
  const void* fmess  = d_in[1];
  const void* agraph = d_in[2];
  const void* bgraph = d_in[3];
  const void* Wz  = d_in[4];
  const void* bz  = d_in[5];
  const void* Wr  = d_in[6];
  const void* Ur  = d_in[7];
  const void* bur = d_in[8];
  const void* Wh  = d_in[9];
  const void* bh  = d_in[10];
  const void* Wo  = d_in[11];
  const void* bo  = d_in[12];

  // workspace (~188 MB): 6 x [E,128] bf16 + fmessB + weights + idx copies
  char* ws = (char*)d_ws;
  bf16_t* Mr  = (bf16_t*)ws; ws += (size_t)E_ * 128 * 2;  // fmess@Wr + bur
  bf16_t* G   = (bf16_t*)ws; ws += (size_t)E_ * 128 * 2;  // h@Ur; later NM
  bf16_t* S   = (bf16_t*)ws; ws += (size_t)E_ * 128 * 2;  // sum h_nei
  bf16_t* T   = (bf16_t*)ws; ws += (size_t)E_ * 128 * 2;  // sum r*h_nei
  bf16_t* hP0 = (bf16_t*)ws; ws += (size_t)E_ * 128 * 2;  // h ping
  bf16_t* hP1 = (bf16_t*)ws; ws += (size_t)E_ * 128 * 2;  // h pong
  bf16_t* fmessB = (bf16_t*)ws; ws += (size_t)E_ * 384 * 2;  // bf16 fmess (f32 rounds)
  bf16_t* WzT = (bf16_t*)ws; ws += 128 * 512 * 2;
  bf16_t* WhT = (bf16_t*)ws; ws += 128 * 512 * 2;
  bf16_t* WrT = (bf16_t*)ws; ws += 128 * 384 * 2;
  bf16_t* UrT = (bf16_t*)ws; ws += 128 * 128 * 2;
  bf16_t* WoT = (bf16_t*)ws; ws += 128 * 384 * 2;
  bf16_t* bzB  = (bf16_t*)ws; ws += 128 * 2;
  bf16_t* burB = (bf16_t*)ws; ws += 128 * 2;
  bf16_t* bhB  = (bf16_t*)ws; ws += 128 * 2;
  bf16_t* boB  = (bf16_t*)ws; ws += 128 * 2;
  int* aI    = (int*)ws; ws += (size_t)N_ * 6 * 4;
  int* bI    = (int*)ws; ws += (size_t)E_ * 6 * 4;
  int* flags = (int*)ws; ws += 16;

  // fnodeB aliases hP1 (same size: 40000*256*2 == 80000*128*2); hP1 is dead
  // after the last depth_gather, which is before cvt_bf16(fnode) runs.
  bf16_t* fnodeB = hP1;

  // OUTPUT AS F32: out0 [N,128] then h [E,128]
  float* out0F = (float*)d_out;
  float* hOutF = out0F + (size_t)N_ * 128;
  bf16_t* NM   = G;   // alias: G dead before nm_gather

  detect<<<1, 64, 0, stream>>>(fmess, bgraph, flags);
  cvt_bf16<<<2048, 256, 0, stream>>>((const float*)fmess, fmessB,
                                     E_ * 384 / 8, flags);
  prep<<<256, 256, 0, stream>>>(Wz, Wr, Ur, Wh, Wo, bz, bur, bh, bo, flags,
                                WzT, WhT, WrT, UrT, WoT, bzB, burB, bhB, boB);
  idx_cvt<<<1875, 256, 0, stream>>>(agraph, bgraph, aI, bI, flags);

  const bf16_t* fmessH = (const bf16_t*)fmess;   // valid when input is bf16
  const bf16_t* fnodeH = (const bf16_t*)fnode;

  // Mr = fmess @ Wr + bur   (loop-invariant)
  mgemm<384, 0, 0><<<625, 512, 0, stream>>>(
      fmessH, fmessB, 384, nullptr, nullptr, WrT, nullptr, 384, flags,
      burB, nullptr, nullptr, Mr, nullptr, E_);

  // depth 0: h = sig(fmess@Wz1+bz) * tanh(fmess@Wh1+bh)  (sum_h = 0)
  mgemm<384, 0, 1><<<625, 512, 0, stream>>>(
      fmessH, fmessB, 384, nullptr, nullptr, WzT, WhT, 512, flags,
      bzB, bhB, nullptr, hP0, nullptr, E_);

  const bf16_t* src = hP0;
  bf16_t* dst = hP1;
  for (int d = 0; d < 2; ++d) {
    // G = h @ Ur
    mgemm<128, 0, 0><<<625, 512, 0, stream>>>(
        src, src, 128, nullptr, nullptr, UrT, nullptr, 128, flags,
        nullptr, nullptr, nullptr, G, nullptr, E_);

    depth_gather<<<5000, 256, 0, stream>>>(src, G, Mr, bI, S, T);

    // h' = (1-z)*S + z*tanh(fmess@Wh1 + T@Wh2 + bh),
    //  z = sig(fmess@Wz1 + S@Wz2 + bz)
    mgemm<384, 128, 1><<<625, 512, 0, stream>>>(
        fmessH, fmessB, 384, S, T, WzT, WhT, 512, flags,
        bzB, bhB, S, dst, (d == 1) ? hOutF : nullptr, E_);

    src = dst;
    dst = (d == 0) ? hP0 : hP1;
  }
  const bf16_t* hFinal = hP0;   // d=1: src was hP1, dst was hP0

  // fnode -> bf16 (into dead hP1)
  cvt_bf16<<<1024, 256, 0, stream>>>((const float*)fnode, fnodeB,
                                     N_ * 256 / 8, flags);

  nm_gather<<<2500, 256, 0, stream>>>(hFinal, aI, NM);

  // out = relu(fnode@Wo1 + NM@Wo2 + bo), row0 = 0   -> f32
  mgemm<256, 128, 2><<<313, 512, 0, stream>>>(
      fnodeH, fnodeB, 256, NM, nullptr, WoT, nullptr, 384, flags,
      boB, nullptr, nullptr, nullptr, out0F, N_);
}